// Round 3
// baseline (297.836 us; speedup 1.0000x reference)
//
#include <hip/hip_runtime.h>

#define NROWS   2097152
#define W       16
#define UNROLL  8
#define NBLOCKS 4096
#define NTHREADS 256
// NBLOCKS*NTHREADS/4 quads * UNROLL == NROWS exactly

__global__ __launch_bounds__(256) void cel_weight_kernel(
    const float* __restrict__ predict,
    const float* __restrict__ target,
    const float* __restrict__ penalty,
    float* __restrict__ out)
{
    __shared__ float s_pen[W * W];
    __shared__ float s_part[4];

    const int tid = threadIdx.x;
    s_pen[tid] = penalty[tid];          // blockDim == W*W == 256
    __syncthreads();

    const int quad  = tid & 3;          // which float4 of the row
    const int jbase = quad * 4;         // column base
    const int q0     = (blockIdx.x * NTHREADS + tid) >> 2;
    const int nquads = (NBLOCKS * NTHREADS) >> 2;   // 262144 rows per sweep

    // ---- issue ALL loads up front: 16 independent coalesced float4 loads ----
    float4 ps[UNROLL], ts[UNROLL];
    #pragma unroll
    for (int k = 0; k < UNROLL; ++k) {
        const size_t off = (size_t)(q0 + k * nquads) * W + jbase;
        ps[k] = *(const float4*)(predict + off);
        ts[k] = *(const float4*)(target + off);
    }

    float acc = 0.0f;

    #pragma unroll
    for (int k = 0; k < UNROLL; ++k) {
        const float4 p = ps[k];
        const float4 t = ts[k];

        // local argmax over this lane's 4 predict elements (first-index tie-break)
        float pmax = p.x; int pidx = jbase;
        if (p.y > pmax) { pmax = p.y; pidx = jbase + 1; }
        if (p.z > pmax) { pmax = p.z; pidx = jbase + 2; }
        if (p.w > pmax) { pmax = p.w; pidx = jbase + 3; }
        #pragma unroll
        for (int d = 1; d <= 2; d <<= 1) {
            float om = __shfl_xor(pmax, d);
            int   oi = __shfl_xor(pidx, d);
            if (om > pmax || (om == pmax && oi < pidx)) { pmax = om; pidx = oi; }
        }

        // softmax denominator (numerator at argmax = 1)
        float lsum = __expf(p.x - pmax) + __expf(p.y - pmax)
                   + __expf(p.z - pmax) + __expf(p.w - pmax);
        lsum += __shfl_xor(lsum, 1);
        lsum += __shfl_xor(lsum, 2);

        // target argmax
        float tmax = t.x; int tidx = jbase;
        if (t.y > tmax) { tmax = t.y; tidx = jbase + 1; }
        if (t.z > tmax) { tmax = t.z; tidx = jbase + 2; }
        if (t.w > tmax) { tmax = t.w; tidx = jbase + 3; }
        #pragma unroll
        for (int d = 1; d <= 2; d <<= 1) {
            float om = __shfl_xor(tmax, d);
            int   oi = __shfl_xor(tidx, d);
            if (om > tmax || (om == tmax && oi < tidx)) { tmax = om; tidx = oi; }
        }

        if (quad == 0) {
            float wgt = (pidx == tidx) ? 0.0f : s_pen[tidx * W + pidx];
            acc += wgt / lsum;
        }
    }

    // wave-64 reduction
    #pragma unroll
    for (int off = 32; off > 0; off >>= 1)
        acc += __shfl_down(acc, off);

    const int lane = tid & 63;
    const int wid  = tid >> 6;
    if (lane == 0) s_part[wid] = acc;
    __syncthreads();

    if (tid == 0) {
        float tot = s_part[0] + s_part[1] + s_part[2] + s_part[3];
        atomicAdd(out, tot * (1.0f / (float)NROWS));
    }
}

extern "C" void kernel_launch(void* const* d_in, const int* in_sizes, int n_in,
                              void* d_out, int out_size, void* d_ws, size_t ws_size,
                              hipStream_t stream)
{
    const float* predict = (const float*)d_in[0];
    const float* target  = (const float*)d_in[1];
    const float* penalty = (const float*)d_in[2];
    float* out = (float*)d_out;

    // d_out is poisoned (0xAA) before every replay — zero it on-stream.
    hipMemsetAsync(out, 0, sizeof(float) * out_size, stream);

    dim3 grid(NBLOCKS), block(NTHREADS);
    cel_weight_kernel<<<grid, block, 0, stream>>>(predict, target, penalty, out);
}

// Round 4
// 283.361 us; speedup vs baseline: 1.0511x; 1.0511x over previous
//
#include <hip/hip_runtime.h>

#define NROWS    2097152
#define W        16
#define NBLOCKS  4096
#define NTHREADS 256
#define NQUADS   ((NBLOCKS * NTHREADS) / 4)   // 262144 rows per sweep
#define ITERS    (NROWS / NQUADS)             // 8, exact

// DPP quad_perm cross-lane (pure VALU, no LDS/lgkmcnt):
//   0xB1 = quad_perm [1,0,3,2]  (xor 1)
//   0x4E = quad_perm [2,3,0,1]  (xor 2)
template <int CTRL>
__device__ __forceinline__ float dpp_f(float x) {
    int r = __builtin_amdgcn_update_dpp(0, __float_as_int(x), CTRL, 0xF, 0xF, true);
    return __int_as_float(r);
}
template <int CTRL>
__device__ __forceinline__ int dpp_i(int x) {
    return __builtin_amdgcn_update_dpp(0, x, CTRL, 0xF, 0xF, true);
}

__global__ __launch_bounds__(256, 6) void cel_weight_kernel(
    const float* __restrict__ predict,
    const float* __restrict__ target,
    const float* __restrict__ penalty,
    float* __restrict__ out)
{
    __shared__ float s_pen[W * W];
    __shared__ float s_part[4];

    const int tid = threadIdx.x;
    s_pen[tid] = penalty[tid];                 // blockDim == 256 == W*W
    __syncthreads();

    const int quad  = tid & 3;
    const int jbase = quad * 4;
    const int q0    = (blockIdx.x * NTHREADS + tid) >> 2;

    const float* pp = predict + (size_t)q0 * W + jbase;
    const float* tp = target  + (size_t)q0 * W + jbase;
    const size_t STEP = (size_t)NQUADS * W;    // elements between k-steps

    // depth-2 register-rotated prefetch pipeline: 4 loads always in flight
    float4 P[2], T[2];
    P[0] = *(const float4*)(pp);
    T[0] = *(const float4*)(tp);
    P[1] = *(const float4*)(pp + STEP);
    T[1] = *(const float4*)(tp + STEP);

    float acc = 0.0f;

    #pragma unroll
    for (int k = 0; k < ITERS; ++k) {
        const float4 p = P[k & 1];
        const float4 t = T[k & 1];
        if (k + 2 < ITERS) {
            P[k & 1] = *(const float4*)(pp + (size_t)(k + 2) * STEP);
            T[k & 1] = *(const float4*)(tp + (size_t)(k + 2) * STEP);
        }

        // ---- predict: quad max (2 DPP), then first-index-of-max (exact eq), quad min
        float m = fmaxf(fmaxf(p.x, p.y), fmaxf(p.z, p.w));
        m = fmaxf(m, dpp_f<0xB1>(m));
        m = fmaxf(m, dpp_f<0x4E>(m));
        int li = 127;
        li = (p.w == m) ? jbase + 3 : li;
        li = (p.z == m) ? jbase + 2 : li;
        li = (p.y == m) ? jbase + 1 : li;
        li = (p.x == m) ? jbase     : li;
        li = min(li, dpp_i<0xB1>(li));
        li = min(li, dpp_i<0x4E>(li));         // pidx (all 4 lanes agree)

        // ---- softmax denominator (numerator at argmax = 1)
        float e = __expf(p.x - m) + __expf(p.y - m)
                + __expf(p.z - m) + __expf(p.w - m);
        e += dpp_f<0xB1>(e);
        e += dpp_f<0x4E>(e);                   // lsum (all 4 lanes agree)

        // ---- target argmax
        float tm = fmaxf(fmaxf(t.x, t.y), fmaxf(t.z, t.w));
        tm = fmaxf(tm, dpp_f<0xB1>(tm));
        tm = fmaxf(tm, dpp_f<0x4E>(tm));
        int ti = 127;
        ti = (t.w == tm) ? jbase + 3 : ti;
        ti = (t.z == tm) ? jbase + 2 : ti;
        ti = (t.y == tm) ? jbase + 1 : ti;
        ti = (t.x == tm) ? jbase     : ti;
        ti = min(ti, dpp_i<0xB1>(ti));
        ti = min(ti, dpp_i<0x4E>(ti));         // tidx

        // all 4 quad lanes accumulate the same term; scaled by 1/4 at the end
        float wgt = (li == ti) ? 0.0f : s_pen[ti * W + li];
        acc += wgt / e;
    }

    // wave-64 reduction
    #pragma unroll
    for (int off = 32; off > 0; off >>= 1)
        acc += __shfl_down(acc, off);

    const int lane = tid & 63;
    const int wid  = tid >> 6;
    if (lane == 0) s_part[wid] = acc;
    __syncthreads();

    if (tid == 0) {
        float tot = s_part[0] + s_part[1] + s_part[2] + s_part[3];
        atomicAdd(out, tot * (0.25f / (float)NROWS));
    }
}

extern "C" void kernel_launch(void* const* d_in, const int* in_sizes, int n_in,
                              void* d_out, int out_size, void* d_ws, size_t ws_size,
                              hipStream_t stream)
{
    const float* predict = (const float*)d_in[0];
    const float* target  = (const float*)d_in[1];
    const float* penalty = (const float*)d_in[2];
    float* out = (float*)d_out;

    // d_out is poisoned (0xAA) before every replay — zero it on-stream.
    hipMemsetAsync(out, 0, sizeof(float) * out_size, stream);

    dim3 grid(NBLOCKS), block(NTHREADS);
    cel_weight_kernel<<<grid, block, 0, stream>>>(predict, target, penalty, out);
}

// Round 5
// 278.700 us; speedup vs baseline: 1.0687x; 1.0167x over previous
//
#include <hip/hip_runtime.h>

#define NROWS    2097152
#define W        16
#define NBLOCKS  2048
#define NTHREADS 256
#define WPB      4                    // waves per block
#define CPW      4                    // chunks per wave
#define CROWS    64                   // rows per chunk (one per lane)
#define CBYTES   (CROWS * W * 4)      // 4096 B per input per chunk
// NBLOCKS * WPB * CPW * CROWS == NROWS exactly

// Fire-and-forget global->LDS DMA, 16 B per lane. HW semantics: LDS dest =
// wave-uniform base + lane*16; global src is per-lane. Counts in vmcnt.
__device__ __forceinline__ void async16(const void* g, void* l) {
    __builtin_amdgcn_global_load_lds(
        (const __attribute__((address_space(1))) void*)g,
        (__attribute__((address_space(3))) void*)l, 16, 0, 0);
}

#define WAITVM(n) asm volatile("s_waitcnt vmcnt(" #n ")" ::: "memory")

__device__ __forceinline__ void stage_chunk(const char* pSrc, const char* tSrc,
                                            float* lp, float* lt, int lane) {
    #pragma unroll
    for (int i = 0; i < 4; ++i) {
        async16(pSrc + i * 1024 + lane * 16, (char*)lp + i * 1024);
        async16(tSrc + i * 1024 + lane * 16, (char*)lt + i * 1024);
    }
}

__global__ __launch_bounds__(256, 2) void cel_weight_kernel(
    const float* __restrict__ predict,
    const float* __restrict__ target,
    const float* __restrict__ penalty,
    float* __restrict__ partials)
{
    __shared__ float sbuf[WPB][2][2][1024];   // [wave][dbuf][input][64 rows x 16]
    __shared__ float s_pen[W * W];
    __shared__ float s_part[WPB];

    const int tid  = threadIdx.x;
    const int w    = tid >> 6;
    const int lane = tid & 63;

    s_pen[tid] = penalty[tid];                // blockDim == 256 == W*W
    __syncthreads();                          // only barrier before the tail

    const int gw = blockIdx.x * WPB + w;      // global wave id
    const int c0 = gw * CPW;                  // this wave's first chunk
    const char* pB = (const char*)predict;
    const char* tB = (const char*)target;

    // prologue: fill both buffers (16 DMAs outstanding)
    stage_chunk(pB + (size_t)c0 * CBYTES, tB + (size_t)c0 * CBYTES,
                &sbuf[w][0][0][0], &sbuf[w][0][1][0], lane);
    stage_chunk(pB + (size_t)(c0 + 1) * CBYTES, tB + (size_t)(c0 + 1) * CBYTES,
                &sbuf[w][1][0][0], &sbuf[w][1][1][0], lane);

    float acc = 0.0f;

    #pragma unroll
    for (int k = 0; k < CPW; ++k) {
        const int db = k & 1;
        if (k < CPW - 1) { WAITVM(8); } else { WAITVM(0); }

        const float* lp = &sbuf[w][db][0][lane * W];
        const float* lt = &sbuf[w][db][1][lane * W];
        float4 p0 = ((const float4*)lp)[0], p1 = ((const float4*)lp)[1],
               p2 = ((const float4*)lp)[2], p3 = ((const float4*)lp)[3];
        float4 t0 = ((const float4*)lt)[0], t1 = ((const float4*)lt)[1],
               t2 = ((const float4*)lt)[2], t3 = ((const float4*)lt)[3];

        // refill this buffer with chunk k+2 (fire-and-forget; lands >=500cyc
        // after the ds_reads above have issued -> no WAR hazard)
        if (k + 2 < CPW) {
            const size_t c = (size_t)(c0 + k + 2);
            stage_chunk(pB + c * CBYTES, tB + c * CBYTES,
                        &sbuf[w][db][0][0], &sbuf[w][db][1][0], lane);
        }

        float pv[W] = {p0.x, p0.y, p0.z, p0.w, p1.x, p1.y, p1.z, p1.w,
                       p2.x, p2.y, p2.z, p2.w, p3.x, p3.y, p3.z, p3.w};
        float tv[W] = {t0.x, t0.y, t0.z, t0.w, t1.x, t1.y, t1.z, t1.w,
                       t2.x, t2.y, t2.z, t2.w, t3.x, t3.y, t3.z, t3.w};

        // argmax(predict), first-index tie-break (matches jnp.argmax)
        float pmax = pv[0]; int pidx = 0;
        #pragma unroll
        for (int j = 1; j < W; ++j)
            if (pv[j] > pmax) { pmax = pv[j]; pidx = j; }

        float s = 0.0f;
        #pragma unroll
        for (int j = 0; j < W; ++j) s += __expf(pv[j] - pmax);

        float tmax = tv[0]; int tidx = 0;
        #pragma unroll
        for (int j = 1; j < W; ++j)
            if (tv[j] > tmax) { tmax = tv[j]; tidx = j; }

        float wgt = (pidx == tidx) ? 0.0f : s_pen[tidx * W + pidx];
        acc += wgt / s;
    }

    // wave-64 reduction, then per-block partial to workspace (no atomics)
    #pragma unroll
    for (int off = 32; off > 0; off >>= 1)
        acc += __shfl_down(acc, off);
    if (lane == 0) s_part[w] = acc;
    __syncthreads();
    if (tid == 0)
        partials[blockIdx.x] = s_part[0] + s_part[1] + s_part[2] + s_part[3];
}

__global__ __launch_bounds__(256) void reduce_kernel(
    const float* __restrict__ partials, float* __restrict__ out)
{
    __shared__ float sp[4];
    const int tid = threadIdx.x;
    float a = 0.0f;
    #pragma unroll
    for (int i = 0; i < NBLOCKS / NTHREADS; ++i)
        a += partials[tid + i * NTHREADS];
    #pragma unroll
    for (int off = 32; off > 0; off >>= 1)
        a += __shfl_down(a, off);
    if ((tid & 63) == 0) sp[tid >> 6] = a;
    __syncthreads();
    if (tid == 0)
        out[0] = (sp[0] + sp[1] + sp[2] + sp[3]) * (1.0f / (float)NROWS);
}

extern "C" void kernel_launch(void* const* d_in, const int* in_sizes, int n_in,
                              void* d_out, int out_size, void* d_ws, size_t ws_size,
                              hipStream_t stream)
{
    const float* predict = (const float*)d_in[0];
    const float* target  = (const float*)d_in[1];
    const float* penalty = (const float*)d_in[2];
    float* out      = (float*)d_out;
    float* partials = (float*)d_ws;   // NBLOCKS floats, fully overwritten

    cel_weight_kernel<<<dim3(NBLOCKS), dim3(NTHREADS), 0, stream>>>(
        predict, target, penalty, partials);
    reduce_kernel<<<dim3(1), dim3(NTHREADS), 0, stream>>>(partials, out);
}